// Round 1
// baseline (473.004 us; speedup 1.0000x reference)
//
#include <hip/hip_runtime.h>
#include <hip/hip_bf16.h>
#include <cmath>

typedef __bf16 bf16_t;
typedef __bf16 bf16x8 __attribute__((ext_vector_type(8)));
typedef float f32x4 __attribute__((ext_vector_type(4)));
typedef unsigned short u16;
typedef unsigned int u32;

// ---------------- async global->LDS (16B per lane) ----------------
__device__ __forceinline__ void load16(const bf16_t* g, bf16_t* l) {
  __builtin_amdgcn_global_load_lds((const __attribute__((address_space(1))) u32*)g,
                                   (__attribute__((address_space(3))) u32*)l, 16, 0, 0);
}

// ---------------- weight transpose + fp32->bf16 ----------------
// Wsrc [Kd][Nd] fp32  ->  Wt [Nd][Kd] bf16
__global__ __launch_bounds__(256) void transpose_w(const float* __restrict__ Wsrc,
                                                   bf16_t* __restrict__ Wt, int Kd, int Nd) {
  __shared__ float tile[32][33];
  int n0 = blockIdx.x * 32, k0 = blockIdx.y * 32;
  int tx = threadIdx.x & 31, ty = threadIdx.x >> 5;  // 32x8
  for (int i = ty; i < 32; i += 8)
    tile[i][tx] = Wsrc[(size_t)(k0 + i) * Nd + n0 + tx];
  __syncthreads();
  for (int i = ty; i < 32; i += 8)
    Wt[(size_t)(n0 + i) * Kd + k0 + tx] = (bf16_t)tile[tx][i];
}

// ---------------- RoPE table: cos/sin [2048][32] ----------------
__global__ void rope_tab(float* __restrict__ c, float* __restrict__ s) {
  int pos = blockIdx.x, t = threadIdx.x;  // 32 threads
  float e = (float)(2 * t) / 64.0f;
  float inv = powf(10000.0f, -e);
  float a = (float)pos * inv;
  c[pos * 32 + t] = cosf(a);
  s[pos * 32 + t] = sinf(a);
}

// ---------------- LayerNorm: one row per block, width W ----------------
template <typename TI, int W>
__global__ __launch_bounds__(256) void ln_kernel(const TI* __restrict__ in,
                                                 const float* __restrict__ g,
                                                 const float* __restrict__ b,
                                                 bf16_t* __restrict__ out) {
  constexpr int PT = W / 256;
  int row = blockIdx.x;
  const TI* p = in + (size_t)row * W;
  float vals[PT];
  float s = 0.f, q = 0.f;
  for (int i = 0; i < PT; ++i) {
    float v = (float)p[threadIdx.x + i * 256];
    vals[i] = v; s += v; q += v * v;
  }
  for (int off = 32; off; off >>= 1) { s += __shfl_xor(s, off); q += __shfl_xor(q, off); }
  __shared__ float red[8];
  int wave = threadIdx.x >> 6, lane = threadIdx.x & 63;
  if (lane == 0) { red[wave] = s; red[4 + wave] = q; }
  __syncthreads();
  s = red[0] + red[1] + red[2] + red[3];
  q = red[4] + red[5] + red[6] + red[7];
  float mu = s * (1.0f / W);
  float var = q * (1.0f / W) - mu * mu;
  float rstd = rsqrtf(var + 1e-5f);
  bf16_t* op = out + (size_t)row * W;
  for (int i = 0; i < PT; ++i) {
    int cix = threadIdx.x + i * 256;
    op[cix] = (bf16_t)((vals[i] - mu) * rstd * g[cix] + b[cix]);
  }
}

// ---------------- GEMM (m97 structure): C[m][n] = sum_k A[m][k]*Bt[n][k] ----------------
// A [M][K] bf16, Bt [Nn][K] bf16. Tile 128x128, BK=32, 4 waves (2x2), 4x4 MFMA tiles/wave.
enum { EPI_QKV = 0, EPI_RESID = 1, EPI_GELU = 2 };

template <int EPI>
__global__ __launch_bounds__(256, 2) void gemm_bt(
    const bf16_t* __restrict__ A, const bf16_t* __restrict__ Bt, int M, int Nn, int K,
    const float* __restrict__ bias, const float* __restrict__ resid,
    float* __restrict__ outf, bf16_t* __restrict__ outb,
    bf16_t* __restrict__ qb, bf16_t* __restrict__ kb, bf16_t* __restrict__ vtb,
    const float* __restrict__ ropeC, const float* __restrict__ ropeS) {
  __shared__ bf16_t lsA[128 * 32];
  __shared__ bf16_t lsB[128 * 32];
  const int tid = threadIdx.x;
  const int lane = tid & 63;
  const int wave = tid >> 6;
  const int l16 = lane & 15, quad = lane >> 4;
  const int wm = (wave >> 1) * 64, wn = (wave & 1) * 64;
  const int m0 = blockIdx.y * 128, n0 = blockIdx.x * 128;

  f32x4 acc[4][4];
  for (int i = 0; i < 4; ++i)
    for (int j = 0; j < 4; ++j) acc[i][j] = {0.f, 0.f, 0.f, 0.f};

  for (int kk = 0; kk < K; kk += 32) {
    __syncthreads();
    for (int i = 0; i < 2; ++i) {
      int s = tid + i * 256;
      int row = s >> 2, ch = s & 3;
      load16(A + (size_t)(m0 + row) * K + kk + ch * 8, lsA + s * 8);
      load16(Bt + (size_t)(n0 + row) * K + kk + ch * 8, lsB + s * 8);
    }
    __syncthreads();
    bf16x8 af[4], bfr[4];
    for (int t = 0; t < 4; ++t) {
      af[t] = *(const bf16x8*)(lsA + (wm + t * 16 + l16) * 32 + quad * 8);
      bfr[t] = *(const bf16x8*)(lsB + (wn + t * 16 + l16) * 32 + quad * 8);
    }
    for (int mt = 0; mt < 4; ++mt)
      for (int nt = 0; nt < 4; ++nt)
        acc[mt][nt] = __builtin_amdgcn_mfma_f32_16x16x32_bf16(af[mt], bfr[nt], acc[mt][nt], 0, 0, 0);
  }

  // epilogue: row = m0+wm+mt*16+quad*4+r, col = n0+wn+nt*16+l16
  for (int mt = 0; mt < 4; ++mt) {
    for (int nt = 0; nt < 4; ++nt) {
      int gn = n0 + wn + nt * 16 + l16;
      int gm0 = m0 + wm + mt * 16 + quad * 4;
      if constexpr (EPI == EPI_QKV) {
        int which = gn >> 10;              // 0=q 1=k 2=v (uniform per nt)
        int hd = gn & 1023, head = hd >> 6, d = hd & 63;
        if (which == 2) {
          // v: pack 4 consecutive pos into one 8B store to vT [bh][d][pos]
          u32 lo, hi;
          {
            float v0 = acc[mt][nt][0] + bias[gn];
            float v1 = acc[mt][nt][1] + bias[gn];
            float v2 = acc[mt][nt][2] + bias[gn];
            float v3 = acc[mt][nt][3] + bias[gn];
            bf16_t b0 = (bf16_t)v0, b1 = (bf16_t)v1, b2 = (bf16_t)v2, b3 = (bf16_t)v3;
            lo = (u32)*(u16*)&b0 | ((u32)*(u16*)&b1 << 16);
            hi = (u32)*(u16*)&b2 | ((u32)*(u16*)&b3 << 16);
          }
          int b = gm0 >> 11, pos = gm0 & 2047;
          int bh = b * 16 + head;
          uint2 pk; pk.x = lo; pk.y = hi;
          *(uint2*)(vtb + ((size_t)bh * 64 + d) * 2048 + pos) = pk;
        } else {
          bf16_t* dst = (which == 0) ? qb : kb;
          int t = d >> 1;
          for (int r = 0; r < 4; ++r) {
            float v = acc[mt][nt][r] + bias[gn];
            float pn = __shfl_xor(v, 1);  // partner column (d^1), same row
            int gm = gm0 + r;
            int b = gm >> 11, pos = gm & 2047;
            float cc = ropeC[pos * 32 + t], ss = ropeS[pos * 32 + t];
            float o = (d & 1) ? (v * cc + pn * ss) : (v * cc - pn * ss);
            dst[(((size_t)(b * 16 + head)) * 2048 + pos) * 64 + d] = (bf16_t)o;
          }
        }
      } else if constexpr (EPI == EPI_GELU) {
        for (int r = 0; r < 4; ++r) {
          int gm = gm0 + r;
          float v = acc[mt][nt][r] + bias[gn];
          float g = 0.5f * v * (1.0f + erff(v * 0.70710678118654752f));
          outb[(size_t)gm * Nn + gn] = (bf16_t)g;
        }
      } else {  // EPI_RESID: out = acc + bias + resid (fp32)
        for (int r = 0; r < 4; ++r) {
          int gm = gm0 + r;
          size_t idx = (size_t)gm * Nn + gn;
          outf[idx] = acc[mt][nt][r] + bias[gn] + resid[idx];
        }
      }
    }
  }
}

// ---------------- Flash attention ----------------
// q,k: [BH][2048][64] bf16 (RoPE applied). vt: [BH][64][2048] bf16.
// o: [B][N][H*64] bf16. grid: (16 q-tiles, 32 bh), 256 threads.
__global__ __launch_bounds__(256, 2) void attn_kernel(
    const bf16_t* __restrict__ q, const bf16_t* __restrict__ k,
    const bf16_t* __restrict__ vt, bf16_t* __restrict__ o) {
  __shared__ bf16_t lsK[128 * 64];
  __shared__ bf16_t lsV[64 * 128];
  __shared__ bf16_t lsP[4][32 * 128];

  const int tid = threadIdx.x, lane = tid & 63, wave = tid >> 6;
  const int l16 = lane & 15, quad = lane >> 4;
  const int bh = blockIdx.y, qt = blockIdx.x;
  const int b = bh >> 4, h = bh & 15;
  const bf16_t* qp = q + (size_t)bh * 2048 * 64;
  const bf16_t* kp = k + (size_t)bh * 2048 * 64;
  const bf16_t* vp = vt + (size_t)bh * 64 * 2048;
  const int qrow0 = qt * 128 + wave * 32;

  // Q fragments in registers, pre-scaled by 1/8 (exact pow2 in bf16)
  bf16x8 qa[2][2];
  for (int mt = 0; mt < 2; ++mt)
    for (int ks = 0; ks < 2; ++ks) {
      bf16x8 t = *(const bf16x8*)(qp + (size_t)(qrow0 + mt * 16 + l16) * 64 + ks * 32 + quad * 8);
      for (int j = 0; j < 8; ++j) t[j] = (bf16_t)((float)t[j] * 0.125f);
      qa[mt][ks] = t;
    }

  f32x4 oacc[2][4];
  for (int i = 0; i < 2; ++i)
    for (int j = 0; j < 4; ++j) oacc[i][j] = {0.f, 0.f, 0.f, 0.f};
  float mrow[2][4], lrow[2][4];
  for (int i = 0; i < 2; ++i)
    for (int r = 0; r < 4; ++r) { mrow[i][r] = -1e30f; lrow[i][r] = 0.f; }

  for (int kt = 0; kt < 16; ++kt) {
    __syncthreads();
    const bf16_t* kg = kp + (size_t)kt * 128 * 64;
    for (int i = 0; i < 4; ++i) {
      int s = tid + i * 256;
      load16(kg + s * 8, lsK + s * 8);              // K tile [n][64], contiguous
      int d = s >> 4, c = s & 15;
      load16(vp + (size_t)d * 2048 + kt * 128 + c * 8, lsV + s * 8);  // V^T tile [d][128]
    }
    __syncthreads();

    // S = (Q/8) K^T : per-wave 32x128
    f32x4 sacc[2][8];
    for (int mt = 0; mt < 2; ++mt)
      for (int nt = 0; nt < 8; ++nt) sacc[mt][nt] = {0.f, 0.f, 0.f, 0.f};
    for (int ks = 0; ks < 2; ++ks)
      for (int nt = 0; nt < 8; ++nt) {
        bf16x8 kf = *(const bf16x8*)(lsK + (nt * 16 + l16) * 64 + ks * 32 + quad * 8);
        for (int mt = 0; mt < 2; ++mt)
          sacc[mt][nt] = __builtin_amdgcn_mfma_f32_16x16x32_bf16(qa[mt][ks], kf, sacc[mt][nt], 0, 0, 0);
      }

    // online softmax; write P to wave-private LDS (C-layout -> A-layout round trip)
    for (int mt = 0; mt < 2; ++mt) {
      for (int r = 0; r < 4; ++r) {
        float mx = sacc[mt][0][r];
        for (int nt = 1; nt < 8; ++nt) mx = fmaxf(mx, sacc[mt][nt][r]);
        for (int off = 1; off < 16; off <<= 1) mx = fmaxf(mx, __shfl_xor(mx, off));
        float mnew = fmaxf(mrow[mt][r], mx);
        float alpha = __expf(mrow[mt][r] - mnew);
        mrow[mt][r] = mnew;
        float rs = 0.f;
        for (int nt = 0; nt < 8; ++nt) {
          float p = __expf(sacc[mt][nt][r] - mnew);
          rs += p;
          lsP[wave][(mt * 16 + quad * 4 + r) * 128 + nt * 16 + l16] = (bf16_t)p;
        }
        for (int off = 1; off < 16; off <<= 1) rs += __shfl_xor(rs, off);
        lrow[mt][r] = lrow[mt][r] * alpha + rs;
        for (int dt = 0; dt < 4; ++dt) oacc[mt][dt][r] *= alpha;
      }
    }

    // O += P V  (P from LDS in A-layout, V^T rows give b-frags)
    for (int ks = 0; ks < 4; ++ks) {
      bf16x8 pf[2];
      for (int mt = 0; mt < 2; ++mt)
        pf[mt] = *(const bf16x8*)(lsP[wave] + (mt * 16 + l16) * 128 + ks * 32 + quad * 8);
      for (int dt = 0; dt < 4; ++dt) {
        bf16x8 vf = *(const bf16x8*)(lsV + (dt * 16 + l16) * 128 + ks * 32 + quad * 8);
        for (int mt = 0; mt < 2; ++mt)
          oacc[mt][dt] = __builtin_amdgcn_mfma_f32_16x16x32_bf16(pf[mt], vf, oacc[mt][dt], 0, 0, 0);
      }
    }
  }

  // epilogue: o[b, row, h*64+d]
  for (int mt = 0; mt < 2; ++mt)
    for (int r = 0; r < 4; ++r) {
      float inv = 1.0f / lrow[mt][r];
      int row = qrow0 + mt * 16 + quad * 4 + r;
      for (int dt = 0; dt < 4; ++dt) {
        int d = dt * 16 + l16;
        o[((size_t)(b * 2048 + row)) * 1024 + h * 64 + d] = (bf16_t)(oacc[mt][dt][r] * inv);
      }
    }
}

// ---------------- launch ----------------
extern "C" void kernel_launch(void* const* d_in, const int* in_sizes, int n_in,
                              void* d_out, int out_size, void* d_ws, size_t ws_size,
                              hipStream_t stream) {
  const float* x = (const float*)d_in[0];
  const float* ln1_g = (const float*)d_in[1];
  const float* ln1_b = (const float*)d_in[2];
  const float* qkv_w = (const float*)d_in[3];
  const float* qkv_b = (const float*)d_in[4];
  const float* proj_w = (const float*)d_in[5];
  const float* proj_b = (const float*)d_in[6];
  const float* ln2_g = (const float*)d_in[7];
  const float* ln2_b = (const float*)d_in[8];
  const float* fc1_w = (const float*)d_in[9];
  const float* fc1_b = (const float*)d_in[10];
  const float* ffg = (const float*)d_in[11];
  const float* ffb = (const float*)d_in[12];
  const float* fc2_w = (const float*)d_in[13];
  const float* fc2_b = (const float*)d_in[14];
  float* out = (float*)d_out;

  char* ws = (char*)d_ws;
  size_t off = 0;
  auto alloc = [&](size_t n) { char* p = ws + off; off += (n + 255) & ~(size_t)255; return p; };

  bf16_t* qkvT  = (bf16_t*)alloc(3072ull * 1024 * 2);
  bf16_t* projT = (bf16_t*)alloc(1024ull * 1024 * 2);
  bf16_t* fc1T  = (bf16_t*)alloc(4096ull * 1024 * 2);
  bf16_t* fc2T  = (bf16_t*)alloc(1024ull * 4096 * 2);
  float*  ropeC = (float*)alloc(2048ull * 32 * 4);
  float*  ropeS = (float*)alloc(2048ull * 32 * 4);
  bf16_t* hx    = (bf16_t*)alloc(4096ull * 1024 * 2);   // LN1 out; reused for LN2 out
  bf16_t* qbuf  = (bf16_t*)alloc(32ull * 2048 * 64 * 2);
  bf16_t* kbuf  = (bf16_t*)alloc(32ull * 2048 * 64 * 2);
  bf16_t* vtbuf = (bf16_t*)alloc(32ull * 64 * 2048 * 2);
  bf16_t* obuf  = (bf16_t*)alloc(4096ull * 1024 * 2);
  float*  x2    = (float*)alloc(4096ull * 1024 * 4);
  bf16_t* h1    = (bf16_t*)alloc(4096ull * 4096 * 2);
  bf16_t* hln   = (bf16_t*)qbuf;  // alias q..o region (33.5MB, dead after proj GEMM)

  // weights -> bf16 transposed
  transpose_w<<<dim3(96, 32), 256, 0, stream>>>(qkv_w, qkvT, 1024, 3072);
  transpose_w<<<dim3(32, 32), 256, 0, stream>>>(proj_w, projT, 1024, 1024);
  transpose_w<<<dim3(128, 32), 256, 0, stream>>>(fc1_w, fc1T, 1024, 4096);
  transpose_w<<<dim3(32, 128), 256, 0, stream>>>(fc2_w, fc2T, 4096, 1024);
  rope_tab<<<2048, 32, 0, stream>>>(ropeC, ropeS);

  // LN1
  ln_kernel<float, 1024><<<4096, 256, 0, stream>>>(x, ln1_g, ln1_b, hx);
  // QKV + RoPE + head scatter
  gemm_bt<EPI_QKV><<<dim3(24, 32), 256, 0, stream>>>(hx, qkvT, 4096, 3072, 1024, qkv_b,
      nullptr, nullptr, nullptr, qbuf, kbuf, vtbuf, ropeC, ropeS);
  // attention
  attn_kernel<<<dim3(16, 32), 256, 0, stream>>>(qbuf, kbuf, vtbuf, obuf);
  // proj + residual -> x2 (fp32)
  gemm_bt<EPI_RESID><<<dim3(8, 32), 256, 0, stream>>>(obuf, projT, 4096, 1024, 1024, proj_b,
      x, x2, nullptr, nullptr, nullptr, nullptr, nullptr, nullptr);
  // LN2 -> hx (bf16)
  ln_kernel<float, 1024><<<4096, 256, 0, stream>>>(x2, ln2_g, ln2_b, hx);
  // FC1 + GELU -> h1 (bf16)
  gemm_bt<EPI_GELU><<<dim3(32, 32), 256, 0, stream>>>(hx, fc1T, 4096, 4096, 1024, fc1_b,
      nullptr, nullptr, h1, nullptr, nullptr, nullptr, nullptr, nullptr);
  // ffn LN over hidden -> hln (bf16)
  ln_kernel<bf16_t, 4096><<<4096, 256, 0, stream>>>(h1, ffg, ffb, hln);
  // FC2 + residual -> out (fp32)
  gemm_bt<EPI_RESID><<<dim3(8, 32), 256, 0, stream>>>(hln, fc2T, 4096, 1024, 4096, fc2_b,
      x2, out, nullptr, nullptr, nullptr, nullptr, nullptr, nullptr);
}

// Round 2
// 432.189 us; speedup vs baseline: 1.0944x; 1.0944x over previous
//
#include <hip/hip_runtime.h>
#include <hip/hip_bf16.h>
#include <cmath>

typedef __bf16 bf16_t;
typedef __bf16 bf16x8 __attribute__((ext_vector_type(8)));
typedef float f32x4 __attribute__((ext_vector_type(4)));
typedef unsigned short u16;
typedef unsigned int u32;

// ---------------- async global->LDS (16B per lane) ----------------
__device__ __forceinline__ void load16(const bf16_t* g, bf16_t* l) {
  __builtin_amdgcn_global_load_lds((const __attribute__((address_space(1))) u32*)g,
                                   (__attribute__((address_space(3))) u32*)l, 16, 0, 0);
}

__device__ __forceinline__ u32 pk2(float a, float b) {
  bf16_t x = (bf16_t)a, y = (bf16_t)b;
  u16 ux = __builtin_bit_cast(u16, x), uy = __builtin_bit_cast(u16, y);
  return (u32)ux | ((u32)uy << 16);
}

union V4U { u32 w[4]; bf16x8 v; };

// ---------------- weight transpose + fp32->bf16 ----------------
__global__ __launch_bounds__(256) void transpose_w(const float* __restrict__ Wsrc,
                                                   bf16_t* __restrict__ Wt, int Kd, int Nd) {
  __shared__ float tile[32][33];
  int n0 = blockIdx.x * 32, k0 = blockIdx.y * 32;
  int tx = threadIdx.x & 31, ty = threadIdx.x >> 5;  // 32x8
  for (int i = ty; i < 32; i += 8)
    tile[i][tx] = Wsrc[(size_t)(k0 + i) * Nd + n0 + tx];
  __syncthreads();
  for (int i = ty; i < 32; i += 8)
    Wt[(size_t)(n0 + i) * Kd + k0 + tx] = (bf16_t)tile[tx][i];
}

// ---------------- RoPE table: cos/sin [2048][32] ----------------
__global__ void rope_tab(float* __restrict__ c, float* __restrict__ s) {
  int pos = blockIdx.x, t = threadIdx.x;  // 32 threads
  float e = (float)(2 * t) / 64.0f;
  float inv = powf(10000.0f, -e);
  float a = (float)pos * inv;
  c[pos * 32 + t] = cosf(a);
  s[pos * 32 + t] = sinf(a);
}

// ---------------- LayerNorm: one row per block, width W ----------------
template <typename TI, int W>
__global__ __launch_bounds__(256) void ln_kernel(const TI* __restrict__ in,
                                                 const float* __restrict__ g,
                                                 const float* __restrict__ b,
                                                 bf16_t* __restrict__ out) {
  constexpr int PT = W / 256;
  int row = blockIdx.x;
  const TI* p = in + (size_t)row * W;
  float vals[PT];
  float s = 0.f, q = 0.f;
  for (int i = 0; i < PT; ++i) {
    float v = (float)p[threadIdx.x + i * 256];
    vals[i] = v; s += v; q += v * v;
  }
  for (int off = 32; off; off >>= 1) { s += __shfl_xor(s, off); q += __shfl_xor(q, off); }
  __shared__ float red[8];
  int wave = threadIdx.x >> 6, lane = threadIdx.x & 63;
  if (lane == 0) { red[wave] = s; red[4 + wave] = q; }
  __syncthreads();
  s = red[0] + red[1] + red[2] + red[3];
  q = red[4] + red[5] + red[6] + red[7];
  float mu = s * (1.0f / W);
  float var = q * (1.0f / W) - mu * mu;
  float rstd = rsqrtf(var + 1e-5f);
  bf16_t* op = out + (size_t)row * W;
  for (int i = 0; i < PT; ++i) {
    int cix = threadIdx.x + i * 256;
    op[cix] = (bf16_t)((vals[i] - mu) * rstd * g[cix] + b[cix]);
  }
}

// ---------------- GEMM (m97 structure): C[m][n] = sum_k A[m][k]*Bt[n][k] ----------------
enum { EPI_QKV = 0, EPI_RESID = 1, EPI_GELU = 2 };

template <int EPI>
__global__ __launch_bounds__(256, 2) void gemm_bt(
    const bf16_t* __restrict__ A, const bf16_t* __restrict__ Bt, int M, int Nn, int K,
    const float* __restrict__ bias, const float* __restrict__ resid,
    float* __restrict__ outf, bf16_t* __restrict__ outb,
    bf16_t* __restrict__ qb, bf16_t* __restrict__ kb, bf16_t* __restrict__ vtb,
    const float* __restrict__ ropeC, const float* __restrict__ ropeS) {
  __shared__ bf16_t lsA[128 * 32];
  __shared__ bf16_t lsB[128 * 32];
  const int tid = threadIdx.x;
  const int lane = tid & 63;
  const int wave = tid >> 6;
  const int l16 = lane & 15, quad = lane >> 4;
  const int wm = (wave >> 1) * 64, wn = (wave & 1) * 64;
  const int m0 = blockIdx.y * 128, n0 = blockIdx.x * 128;

  f32x4 acc[4][4];
  for (int i = 0; i < 4; ++i)
    for (int j = 0; j < 4; ++j) acc[i][j] = {0.f, 0.f, 0.f, 0.f};

  for (int kk = 0; kk < K; kk += 32) {
    __syncthreads();
    for (int i = 0; i < 2; ++i) {
      int s = tid + i * 256;
      int row = s >> 2, ch = s & 3;
      load16(A + (size_t)(m0 + row) * K + kk + ch * 8, lsA + s * 8);
      load16(Bt + (size_t)(n0 + row) * K + kk + ch * 8, lsB + s * 8);
    }
    __syncthreads();
    bf16x8 af[4], bfr[4];
    for (int t = 0; t < 4; ++t) {
      af[t] = *(const bf16x8*)(lsA + (wm + t * 16 + l16) * 32 + quad * 8);
      bfr[t] = *(const bf16x8*)(lsB + (wn + t * 16 + l16) * 32 + quad * 8);
    }
    for (int mt = 0; mt < 4; ++mt)
      for (int nt = 0; nt < 4; ++nt)
        acc[mt][nt] = __builtin_amdgcn_mfma_f32_16x16x32_bf16(af[mt], bfr[nt], acc[mt][nt], 0, 0, 0);
  }

  // epilogue: row = m0+wm+mt*16+quad*4+r, col = n0+wn+nt*16+l16
  for (int mt = 0; mt < 4; ++mt) {
    for (int nt = 0; nt < 4; ++nt) {
      int gn = n0 + wn + nt * 16 + l16;
      int gm0 = m0 + wm + mt * 16 + quad * 4;
      if constexpr (EPI == EPI_QKV) {
        int which = gn >> 10;              // 0=q 1=k 2=v (uniform per nt)
        int hd = gn & 1023, head = hd >> 6, d = hd & 63;
        if (which == 2) {
          u32 lo, hi;
          {
            float v0 = acc[mt][nt][0] + bias[gn];
            float v1 = acc[mt][nt][1] + bias[gn];
            float v2 = acc[mt][nt][2] + bias[gn];
            float v3 = acc[mt][nt][3] + bias[gn];
            lo = pk2(v0, v1);
            hi = pk2(v2, v3);
          }
          int b = gm0 >> 11, pos = gm0 & 2047;
          int bh = b * 16 + head;
          uint2 pk; pk.x = lo; pk.y = hi;
          *(uint2*)(vtb + ((size_t)bh * 64 + d) * 2048 + pos) = pk;
        } else {
          bf16_t* dst = (which == 0) ? qb : kb;
          int t = d >> 1;
          for (int r = 0; r < 4; ++r) {
            float v = acc[mt][nt][r] + bias[gn];
            float pn = __shfl_xor(v, 1);  // partner column (d^1), same row
            int gm = gm0 + r;
            int b = gm >> 11, pos = gm & 2047;
            float cc = ropeC[pos * 32 + t], ss = ropeS[pos * 32 + t];
            float o = (d & 1) ? (v * cc + pn * ss) : (v * cc - pn * ss);
            dst[(((size_t)(b * 16 + head)) * 2048 + pos) * 64 + d] = (bf16_t)o;
          }
        }
      } else if constexpr (EPI == EPI_GELU) {
        for (int r = 0; r < 4; ++r) {
          int gm = gm0 + r;
          float v = acc[mt][nt][r] + bias[gn];
          float g = 0.5f * v * (1.0f + erff(v * 0.70710678118654752f));
          outb[(size_t)gm * Nn + gn] = (bf16_t)g;
        }
      } else {  // EPI_RESID: out = acc + bias + resid (fp32)
        for (int r = 0; r < 4; ++r) {
          int gm = gm0 + r;
          size_t idx = (size_t)gm * Nn + gn;
          outf[idx] = acc[mt][nt][r] + bias[gn] + resid[idx];
        }
      }
    }
  }
}

// ---------------- Flash attention (S^T orientation, no P round-trip) ----------------
// q,k: [BH][2048][64] bf16 (RoPE applied). vt: [BH][64][2048] bf16.
// o: [B][N][H*64] bf16. grid: (16 q-tiles, 32 bh), 256 threads, 32 q-rows/wave.
// lsK/lsV use XOR-swizzled 16B chunks: chunk c of row r stored at c ^ (r&7).
__global__ __launch_bounds__(256, 2) void attn_kernel(
    const bf16_t* __restrict__ q, const bf16_t* __restrict__ k,
    const bf16_t* __restrict__ vt, bf16_t* __restrict__ o) {
  __shared__ bf16_t lsK[128 * 64];   // [key row][d], swizzled chunks
  __shared__ bf16_t lsV[64 * 128];   // [d][key], swizzled chunks

  const int tid = threadIdx.x, lane = tid & 63, wave = tid >> 6;
  const int l16 = lane & 15, quad = lane >> 4;
  const int bh = blockIdx.y, qt = blockIdx.x;
  const int b = bh >> 4, h = bh & 15;
  const bf16_t* qp = q + (size_t)bh * 2048 * 64;
  const bf16_t* kp = k + (size_t)bh * 2048 * 64;
  const bf16_t* vp = vt + (size_t)bh * 64 * 2048;
  const int qrow0 = qt * 128 + wave * 32;

  // Q fragments (B-operand for S^T), pre-scaled by 1/8 (exact in bf16)
  bf16x8 qa[2][2];
#pragma unroll
  for (int mt = 0; mt < 2; ++mt)
#pragma unroll
    for (int ks = 0; ks < 2; ++ks) {
      bf16x8 t = *(const bf16x8*)(qp + (size_t)(qrow0 + mt * 16 + l16) * 64 + ks * 32 + quad * 8);
#pragma unroll
      for (int j = 0; j < 8; ++j) t[j] = (bf16_t)((float)t[j] * 0.125f);
      qa[mt][ks] = t;
    }

  f32x4 oacc[2][4];
#pragma unroll
  for (int i = 0; i < 2; ++i)
#pragma unroll
    for (int j = 0; j < 4; ++j) oacc[i][j] = {0.f, 0.f, 0.f, 0.f};
  float mstate[2] = {-1e30f, -1e30f};
  float lstate[2] = {0.f, 0.f};

  for (int kt = 0; kt < 16; ++kt) {
    __syncthreads();
    const bf16_t* kg = kp + (size_t)kt * 128 * 64;
#pragma unroll
    for (int i = 0; i < 4; ++i) {
      int s = tid + i * 256;
      // K: 128 rows x 8 chunks; slot s holds global chunk (s&7)^((s>>3)&7) of row s>>3
      int kr = s >> 3, kc = (s & 7) ^ (kr & 7);
      load16(kg + (size_t)kr * 64 + kc * 8, lsK + s * 8);
      // V^T: 64 rows x 16 chunks; slot s holds global chunk ((s&15)^((s>>4)&7)) of row s>>4
      int vr = s >> 4, vc = (s & 15) ^ (vr & 7);
      load16(vp + (size_t)vr * 2048 + kt * 128 + vc * 8, lsV + s * 8);
    }
    __syncthreads();

    // S^T = mfma(K, Q): sacc[nt][mt][r] = S[qrow=mt*16+l16][key=nt*16+quad*4+r]
    f32x4 sacc[8][2];
#pragma unroll
    for (int nt = 0; nt < 8; ++nt)
#pragma unroll
      for (int mt = 0; mt < 2; ++mt) sacc[nt][mt] = {0.f, 0.f, 0.f, 0.f};
#pragma unroll
    for (int ks = 0; ks < 2; ++ks)
#pragma unroll
      for (int nt = 0; nt < 8; ++nt) {
        int rr = nt * 16 + l16;
        int cs = (ks * 4 + quad) ^ (rr & 7);
        bf16x8 kf = *(const bf16x8*)(lsK + rr * 64 + cs * 8);
        sacc[nt][0] = __builtin_amdgcn_mfma_f32_16x16x32_bf16(kf, qa[0][ks], sacc[nt][0], 0, 0, 0);
        sacc[nt][1] = __builtin_amdgcn_mfma_f32_16x16x32_bf16(kf, qa[1][ks], sacc[nt][1], 0, 0, 0);
      }

    // online softmax per mt (row = q-row = l16-indexed; reduce in-lane + cross-quad)
    u32 u[2][8][2];
#pragma unroll
    for (int mt = 0; mt < 2; ++mt) {
      float mx = sacc[0][mt][0];
#pragma unroll
      for (int nt = 0; nt < 8; ++nt)
#pragma unroll
        for (int r = 0; r < 4; ++r) mx = fmaxf(mx, sacc[nt][mt][r]);
      mx = fmaxf(mx, __shfl_xor(mx, 16));
      mx = fmaxf(mx, __shfl_xor(mx, 32));
      float mnew = fmaxf(mstate[mt], mx);
      float alpha = __expf(mstate[mt] - mnew);
      mstate[mt] = mnew;
      float rs = 0.f;
#pragma unroll
      for (int nt = 0; nt < 8; ++nt) {
        float p0 = __expf(sacc[nt][mt][0] - mnew);
        float p1 = __expf(sacc[nt][mt][1] - mnew);
        float p2 = __expf(sacc[nt][mt][2] - mnew);
        float p3 = __expf(sacc[nt][mt][3] - mnew);
        rs += (p0 + p1) + (p2 + p3);
        u[mt][nt][0] = pk2(p0, p1);
        u[mt][nt][1] = pk2(p2, p3);
      }
      rs += __shfl_xor(rs, 16);
      rs += __shfl_xor(rs, 32);
      lstate[mt] = lstate[mt] * alpha + rs;
      // rescale O: alpha for row mt*16+quad*4+r lives at lane l16=quad*4+r (quad 0 grp)
#pragma unroll
      for (int r = 0; r < 4; ++r) {
        float a = __shfl(alpha, quad * 4 + r);
#pragma unroll
        for (int dt = 0; dt < 4; ++dt) oacc[mt][dt][r] *= a;
      }
    }

    // O += P V. A-frag(P) built by cross-quad shuffles of packed u32s.
#pragma unroll
    for (int ks = 0; ks < 4; ++ks) {
      bf16x8 pf[2];
#pragma unroll
      for (int mt = 0; mt < 2; ++mt) {
        V4U a;
#pragma unroll
        for (int w = 0; w < 4; ++w) {
          int src = ((quad & 1) * 2 + (w >> 1)) * 16 + l16;
          u32 lo = (u32)__shfl((int)u[mt][2 * ks + 0][w & 1], src);
          u32 hi = (u32)__shfl((int)u[mt][2 * ks + 1][w & 1], src);
          a.w[w] = (quad & 2) ? hi : lo;
        }
        pf[mt] = a.v;
      }
#pragma unroll
      for (int dt = 0; dt < 4; ++dt) {
        int rd = dt * 16 + l16;
        int cs = (ks * 4 + quad) ^ (rd & 7);
        bf16x8 vf = *(const bf16x8*)(lsV + rd * 128 + cs * 8);
        oacc[0][dt] = __builtin_amdgcn_mfma_f32_16x16x32_bf16(pf[0], vf, oacc[0][dt], 0, 0, 0);
        oacc[1][dt] = __builtin_amdgcn_mfma_f32_16x16x32_bf16(pf[1], vf, oacc[1][dt], 0, 0, 0);
      }
    }
  }

  // epilogue: o[b, row, h*64+d]; 1/l for row mt*16+quad*4+r from lane quad*4+r
#pragma unroll
  for (int mt = 0; mt < 2; ++mt) {
    float inv = 1.0f / lstate[mt];
#pragma unroll
    for (int r = 0; r < 4; ++r) {
      float li = __shfl(inv, quad * 4 + r);
      int row = qrow0 + mt * 16 + quad * 4 + r;
#pragma unroll
      for (int dt = 0; dt < 4; ++dt) {
        int d = dt * 16 + l16;
        o[((size_t)(b * 2048 + row)) * 1024 + h * 64 + d] = (bf16_t)(oacc[mt][dt][r] * li);
      }
    }
  }
}

// ---------------- launch ----------------
extern "C" void kernel_launch(void* const* d_in, const int* in_sizes, int n_in,
                              void* d_out, int out_size, void* d_ws, size_t ws_size,
                              hipStream_t stream) {
  const float* x = (const float*)d_in[0];
  const float* ln1_g = (const float*)d_in[1];
  const float* ln1_b = (const float*)d_in[2];
  const float* qkv_w = (const float*)d_in[3];
  const float* qkv_b = (const float*)d_in[4];
  const float* proj_w = (const float*)d_in[5];
  const float* proj_b = (const float*)d_in[6];
  const float* ln2_g = (const float*)d_in[7];
  const float* ln2_b = (const float*)d_in[8];
  const float* fc1_w = (const float*)d_in[9];
  const float* fc1_b = (const float*)d_in[10];
  const float* ffg = (const float*)d_in[11];
  const float* ffb = (const float*)d_in[12];
  const float* fc2_w = (const float*)d_in[13];
  const float* fc2_b = (const float*)d_in[14];
  float* out = (float*)d_out;

  char* ws = (char*)d_ws;
  size_t off = 0;
  auto alloc = [&](size_t n) { char* p = ws + off; off += (n + 255) & ~(size_t)255; return p; };

  bf16_t* qkvT  = (bf16_t*)alloc(3072ull * 1024 * 2);
  bf16_t* projT = (bf16_t*)alloc(1024ull * 1024 * 2);
  bf16_t* fc1T  = (bf16_t*)alloc(4096ull * 1024 * 2);
  bf16_t* fc2T  = (bf16_t*)alloc(1024ull * 4096 * 2);
  float*  ropeC = (float*)alloc(2048ull * 32 * 4);
  float*  ropeS = (float*)alloc(2048ull * 32 * 4);
  bf16_t* hx    = (bf16_t*)alloc(4096ull * 1024 * 2);   // LN1 out; reused for LN2 out
  bf16_t* qbuf  = (bf16_t*)alloc(32ull * 2048 * 64 * 2);
  bf16_t* kbuf  = (bf16_t*)alloc(32ull * 2048 * 64 * 2);
  bf16_t* vtbuf = (bf16_t*)alloc(32ull * 64 * 2048 * 2);
  bf16_t* obuf  = (bf16_t*)alloc(4096ull * 1024 * 2);
  float*  x2    = (float*)alloc(4096ull * 1024 * 4);
  bf16_t* h1    = (bf16_t*)alloc(4096ull * 4096 * 2);
  bf16_t* hln   = (bf16_t*)qbuf;  // alias q..o region (dead after proj GEMM)

  // weights -> bf16 transposed
  transpose_w<<<dim3(96, 32), 256, 0, stream>>>(qkv_w, qkvT, 1024, 3072);
  transpose_w<<<dim3(32, 32), 256, 0, stream>>>(proj_w, projT, 1024, 1024);
  transpose_w<<<dim3(128, 32), 256, 0, stream>>>(fc1_w, fc1T, 1024, 4096);
  transpose_w<<<dim3(32, 128), 256, 0, stream>>>(fc2_w, fc2T, 4096, 1024);
  rope_tab<<<2048, 32, 0, stream>>>(ropeC, ropeS);

  // LN1
  ln_kernel<float, 1024><<<4096, 256, 0, stream>>>(x, ln1_g, ln1_b, hx);
  // QKV + RoPE + head scatter
  gemm_bt<EPI_QKV><<<dim3(24, 32), 256, 0, stream>>>(hx, qkvT, 4096, 3072, 1024, qkv_b,
      nullptr, nullptr, nullptr, qbuf, kbuf, vtbuf, ropeC, ropeS);
  // attention
  attn_kernel<<<dim3(16, 32), 256, 0, stream>>>(qbuf, kbuf, vtbuf, obuf);
  // proj + residual -> x2 (fp32)
  gemm_bt<EPI_RESID><<<dim3(8, 32), 256, 0, stream>>>(obuf, projT, 4096, 1024, 1024, proj_b,
      x, x2, nullptr, nullptr, nullptr, nullptr, nullptr, nullptr);
  // LN2 -> hx (bf16)
  ln_kernel<float, 1024><<<4096, 256, 0, stream>>>(x2, ln2_g, ln2_b, hx);
  // FC1 + GELU -> h1 (bf16)
  gemm_bt<EPI_GELU><<<dim3(32, 32), 256, 0, stream>>>(hx, fc1T, 4096, 4096, 1024, fc1_b,
      nullptr, nullptr, h1, nullptr, nullptr, nullptr, nullptr, nullptr);
  // ffn LN over hidden -> hln (bf16)
  ln_kernel<bf16_t, 4096><<<4096, 256, 0, stream>>>(h1, ffg, ffb, hln);
  // FC2 + residual -> out (fp32)
  gemm_bt<EPI_RESID><<<dim3(8, 32), 256, 0, stream>>>(hln, fc2T, 4096, 1024, 4096, fc2_b,
      x2, out, nullptr, nullptr, nullptr, nullptr, nullptr, nullptr);
}